// Round 5
// baseline (125.387 us; speedup 1.0000x reference)
//
#include <hip/hip_runtime.h>
#include <math.h>

typedef short bf16x8 __attribute__((ext_vector_type(8)));
typedef float f32x4 __attribute__((ext_vector_type(4)));
typedef unsigned short u16;
typedef unsigned int u32;

#define RFL(x) __builtin_amdgcn_readfirstlane(x)

static __device__ __forceinline__ float bf2f(u16 s) {
  union { u32 u; float f; } c; c.u = ((u32)s) << 16; return c.f;
}
static __device__ __forceinline__ u16 f2bf(float f) {
  union { float f; u32 u; } c; c.f = f;
  u32 u = c.u + 0x7fffu + ((c.u >> 16) & 1u);
  return (u16)(u >> 16);
}
static __device__ __forceinline__ u32 pk2(float lo, float hi) {
  u32 r;
  asm("v_cvt_pk_bf16_f32 %0, %1, %2" : "=v"(r) : "v"(lo), "v"(hi));
  return r;
}
static __device__ __forceinline__ f32x4 MF(bf16x8 a, bf16x8 b, f32x4 c) {
  return __builtin_amdgcn_mfma_f32_16x16x32_bf16(a, b, c, 0, 0, 0);
}

// B=16, D=64, L=1280, H=8, hd=8, WIN=5, DFF=128
// Token-major layouts: XT[20480][64] bf16; QKV[20480][384] bf16
//   cols: [0:64)Qloc(*sc) [64:128)Kloc [128:192)Vloc [192:256)Qg(*sc*log2e)
//         [256:320)Kg [320:384)Vg
// MFMA 16x16x32 bf16: A: lane->m=l&15,k=8*(l>>4)+j ; B: lane->k=8*(l>>4)+j,n=l&15
//   C/D: lane,reg r -> row=4*(l>>4)+r, col=l&15

// ============ K0: x -> XT bf16 (transpose) + weights -> bf16 ============
__global__ __launch_bounds__(256) void prep_kernel(
    const float* __restrict__ x,
    const float* __restrict__ lw_in, const float* __restrict__ gw_in,
    const float* __restrict__ lw_out, const float* __restrict__ gw_out,
    const float* __restrict__ w1, const float* __restrict__ w2,
    u16* __restrict__ XT, u16* __restrict__ Wqkv,
    u16* __restrict__ Wlout, u16* __restrict__ Wgout,
    u16* __restrict__ W1b, u16* __restrict__ W2b) {
  const int t = threadIdx.x;
  if (blockIdx.x < 320) {
    __shared__ __align__(16) float xs[64][68];
    const int b = blockIdx.x / 20, l0 = (blockIdx.x % 20) * 64;
    for (int i = t; i < 4096; i += 256) {
      const int d = i >> 6, tok = i & 63;
      xs[tok][d] = x[(b * 64 + d) * 1280 + l0 + tok];
    }
    __syncthreads();
    for (int i = t; i < 512; i += 256) {
      const int tok = i >> 3, c8 = (i & 7) * 8;
      union { bf16x8 v; u32 u[4]; } o;
      const float* src = &xs[tok][c8];
      o.u[0] = pk2(src[0], src[1]); o.u[1] = pk2(src[2], src[3]);
      o.u[2] = pk2(src[4], src[5]); o.u[3] = pk2(src[6], src[7]);
      *(bf16x8*)(XT + (b * 1280 + l0 + tok) * 64 + c8) = o.v;
    }
  } else {
    const int wb = blockIdx.x - 320;
    for (int f = wb * 256 + t; f < 49152; f += 24 * 256) {
      if (f < 12288)      Wqkv[f] = f2bf(lw_in[f]);
      else if (f < 24576) Wqkv[f] = f2bf(gw_in[f - 12288]);
      else if (f < 28672) Wlout[f - 24576] = f2bf(lw_out[f - 24576]);
      else if (f < 32768) Wgout[f - 28672] = f2bf(gw_out[f - 28672]);
      else if (f < 40960) W1b[f - 32768] = f2bf(w1[f - 32768]);
      else                W2b[f - 40960] = f2bf(w2[f - 40960]);
    }
  }
}

// ============ K1: QKV GEMM (local+global fused), M=20480 N=384 K=64 ======
__global__ __launch_bounds__(256) void qkv_gemm(
    const u16* __restrict__ XT, const u16* __restrict__ Wqkv,
    const float* __restrict__ lb_in, const float* __restrict__ gb_in,
    u16* __restrict__ QKV) {
  const int t = threadIdx.x;
  const int lane = t & 63, w = RFL(t >> 6);
  const int lr = lane & 15, lg = lane >> 4;
  const int m0 = blockIdx.x * 64 + (w & 1) * 32;
  const int n0 = blockIdx.y * 96 + (w >> 1) * 48;
  bf16x8 a[2][2], bb[3][2];
#pragma unroll
  for (int mt = 0; mt < 2; ++mt)
#pragma unroll
    for (int ks = 0; ks < 2; ++ks)
      a[mt][ks] = *(const bf16x8*)(XT + (m0 + mt * 16 + lr) * 64 + ks * 32 + lg * 8);
#pragma unroll
  for (int nt = 0; nt < 3; ++nt)
#pragma unroll
    for (int ks = 0; ks < 2; ++ks)
      bb[nt][ks] = *(const bf16x8*)(Wqkv + (n0 + nt * 16 + lr) * 64 + ks * 32 + lg * 8);
  f32x4 acc[2][3];
#pragma unroll
  for (int mt = 0; mt < 2; ++mt)
#pragma unroll
    for (int nt = 0; nt < 3; ++nt) {
      f32x4 z = {0.f, 0.f, 0.f, 0.f};
      acc[mt][nt] = z;
#pragma unroll
      for (int ks = 0; ks < 2; ++ks)
        acc[mt][nt] = MF(a[mt][ks], bb[nt][ks], acc[mt][nt]);
    }
#pragma unroll
  for (int nt = 0; nt < 3; ++nt) {
    const int col = n0 + nt * 16 + lr;
    const float bias = (col < 192) ? lb_in[col] : gb_in[col - 192];
    // fold softmax scale into Q (local: sc; global: sc*log2e for exp2)
    const float scale = (col < 64) ? 0.35355339059327373f
                      : ((col >= 192 && col < 256) ? 0.51010407600615432f : 1.f);
#pragma unroll
    for (int mt = 0; mt < 2; ++mt)
#pragma unroll
      for (int r = 0; r < 4; ++r) {
        const int row = m0 + mt * 16 + 4 * lg + r;
        QKV[row * 384 + col] = f2bf((acc[mt][nt][r] + bias) * scale);
      }
  }
}

// ============ K2: local windowed attention (WIN=5, Q pre-scaled) =========
__global__ __launch_bounds__(256) void latt(const u16* __restrict__ QKV,
                                            u16* __restrict__ AOl) {
  const int g = blockIdx.x * 256 + threadIdx.x;
  const int qi = g % 5, h = (g / 5) & 7, wi = (g / 40) & 255, b = g / 10240;
  const int row = b * 1280 + wi * 5 + qi;
  float q[8];
  {
    bf16x8 qv = *(const bf16x8*)(QKV + row * 384 + h * 8);
#pragma unroll
    for (int d = 0; d < 8; ++d) q[d] = bf2f((u16)qv[d]);
  }
  float p[5], sum = 0.f;
#pragma unroll
  for (int j = 0; j < 5; ++j) {
    const int krow = b * 1280 + wi * 5 + j;
    bf16x8 kv = *(const bf16x8*)(QKV + krow * 384 + 64 + h * 8);
    float s = 0.f;
#pragma unroll
    for (int d = 0; d < 8; ++d) s = fmaf(q[d], bf2f((u16)kv[d]), s);
    p[j] = __expf(s); sum += p[j];
  }
  const float inv = 1.f / sum;
  float o[8] = {0, 0, 0, 0, 0, 0, 0, 0};
#pragma unroll
  for (int j = 0; j < 5; ++j) {
    const int vrow = b * 1280 + wi * 5 + j;
    bf16x8 vv = *(const bf16x8*)(QKV + vrow * 384 + 128 + h * 8);
#pragma unroll
    for (int d = 0; d < 8; ++d) o[d] = fmaf(p[j], bf2f((u16)vv[d]), o[d]);
  }
  union { bf16x8 v; u32 u[4]; } ov;
  ov.u[0] = pk2(o[0] * inv, o[1] * inv); ov.u[1] = pk2(o[2] * inv, o[3] * inv);
  ov.u[2] = pk2(o[4] * inv, o[5] * inv); ov.u[3] = pk2(o[6] * inv, o[7] * inv);
  *(bf16x8*)(AOl + row * 64 + h * 8) = ov.v;
}

// ============ K3: global attention, MFMA flash =============================
// Bank-conflict-audited LDS layout:
//  Klds: 1280 K-rows (16B each) + 136-u16 zero pad (lanes>=16 read kf0@10240,
//        kf1@10368..10375 -> inside pad).
//  VT:   rows d=0..7 = V^T, row 8 = ones (PV output row 8 = softmax denom).
//        Row stride 1292 u16 -> byte stride 2584 -> bank quad (6*row) mod 32:
//        ~2-way max on the b128 read.
//  Pb:   per-wave P tile [16 q][stride 40 u16] (R2-proven): write bank
//        (20c+2lg) mod 32, read quad (20c+4lg) mod 32 -> ~2-way, near-free.
__global__ __launch_bounds__(512) void gatt(const u16* __restrict__ QKV,
                                            u16* __restrict__ AOg) {
  __shared__ __align__(16) u16 Klds[10376];   // 1280*8 + 136 zero pad
  __shared__ __align__(16) u16 VT[9 * 1292];  // V^T d=0..7; row 8 = ones
  __shared__ __align__(16) u16 Pb[8 * 640];   // per-wave P tiles, stride 40
  const int t = threadIdx.x;
  const int b = blockIdx.y >> 3, h = blockIdx.y & 7;
  for (int l = t; l < 1280; l += 512) {
    const int src = (b * 1280 + l) * 384 + h * 8;
    bf16x8 kv = *(const bf16x8*)(QKV + src + 256);
    bf16x8 vv = *(const bf16x8*)(QKV + src + 320);
    *(bf16x8*)(Klds + l * 8) = kv;
#pragma unroll
    for (int d = 0; d < 8; ++d) VT[d * 1292 + l] = (u16)vv[d];
  }
  if (t < 68) *(u32*)(Klds + 10240 + t * 2) = 0;             // 136 u16 zeros
  for (int l = t; l < 1292; l += 512) VT[8 * 1292 + l] = 0x3F80;  // ones row
  __syncthreads();
  const int lane = t & 63, w = RFL(t >> 6);
  const int c = lane & 15, lg = lane >> 4;
  const int q0 = blockIdx.x * 128 + w * 16;
  const int qrow = b * 1280 + q0 + c;
  const bf16x8 qf = *(const bf16x8*)(QKV + qrow * 384 + 192 + h * 8);
  const u16* kp = Klds + ((lane < 16) ? c * 8 : 10240);
  const int kinc = (lane < 16) ? 256 : 0;
  const int vrow = (c < 8) ? c : 8;
  const u16* vp = VT + vrow * 1292 + lg * 8;
  u16* pw = Pb + w * 640 + c * 40 + lg * 4;
  const u16* pr = Pb + w * 640 + c * 40 + lg * 8;
  f32x4 oacc = {0.f, 0.f, 0.f, 0.f};
#pragma unroll 2
  for (int jt = 0; jt < 40; ++jt) {
    bf16x8 kf0 = *(const bf16x8*)kp;
    bf16x8 kf1 = *(const bf16x8*)(kp + 128);
    f32x4 z = {0.f, 0.f, 0.f, 0.f};
    f32x4 s0 = MF(kf0, qf, z);   // S^T[32jt+4lg+r][q0+c]
    f32x4 s1 = MF(kf1, qf, z);   // +16
    const float p0 = __builtin_amdgcn_exp2f(s0[0]);
    const float p1 = __builtin_amdgcn_exp2f(s0[1]);
    const float p2 = __builtin_amdgcn_exp2f(s0[2]);
    const float p3 = __builtin_amdgcn_exp2f(s0[3]);
    const float p4 = __builtin_amdgcn_exp2f(s1[0]);
    const float p5 = __builtin_amdgcn_exp2f(s1[1]);
    const float p6 = __builtin_amdgcn_exp2f(s1[2]);
    const float p7 = __builtin_amdgcn_exp2f(s1[3]);
    uint2 w01, w23;
    w01.x = pk2(p0, p1); w01.y = pk2(p2, p3);
    w23.x = pk2(p4, p5); w23.y = pk2(p6, p7);
    *(uint2*)pw = w01;               // row c, cols 4lg..4lg+3
    *(uint2*)(pw + 16) = w23;        // row c, cols 16+4lg..
    asm volatile("" ::: "memory");   // order P write -> P read
    bf16x8 pb = *(const bf16x8*)pr;  // B: P[32jt+8lg+j'][q0+c]
    bf16x8 vf = *(const bf16x8*)vp;  // A: V^T[d=c][...]; ones for c>=8
    oacc = MF(vf, pb, oacc);         // out^T[d][q]; row 8 = sum P
    kp += kinc; vp += 32;
  }
  const float ssum = __shfl(oacc[0], 32 + c);  // D[8][c] lives in lane 32+c
  const float inv = 1.f / ssum;
  if (lg < 2) {                                // d = 4*lg + r in [0,8)
    const int base = qrow * 64 + h * 8 + lg * 4;
    *(u32*)(AOg + base) = pk2(oacc[0] * inv, oacc[1] * inv);
    *(u32*)(AOg + base + 2) = pk2(oacc[2] * inv, oacc[3] * inv);
  }
}

// ============ K4: proj+res+LN (x2) + gate + FFN + LN3 + transpose ========
__global__ __launch_bounds__(256) void tail_kernel(
    const u16* __restrict__ AOl, const u16* __restrict__ AOg,
    const u16* __restrict__ Wlout, const u16* __restrict__ Wgout,
    const u16* __restrict__ W1b, const u16* __restrict__ W2b,
    const float* __restrict__ lb_out, const float* __restrict__ gb_out,
    const float* __restrict__ lwt,
    const float* __restrict__ g1, const float* __restrict__ b1,
    const float* __restrict__ g2, const float* __restrict__ b2,
    const float* __restrict__ g3, const float* __restrict__ b3,
    const float* __restrict__ bf1, const float* __restrict__ bf2,
    const float* __restrict__ x, float* __restrict__ out) {
  __shared__ __align__(16) float xso[64][68];   // residual in, out^T at end
  __shared__ __align__(16) u16 Ft[64 * 64];     // fused (XOR-swizzled)
  __shared__ __align__(16) u16 Ht[64 * 128];    // ffn hidden (XOR-swizzled)
  const int t = threadIdx.x;
  const int b = blockIdx.y, l0 = blockIdx.x * 64;
  for (int i = t; i < 4096; i += 256) {
    const int d = i >> 6, tok = i & 63;
    xso[d][tok] = x[(b * 64 + d) * 1280 + l0 + tok];
  }
  __syncthreads();
  const int lane = t & 63, w = RFL(t >> 6);
  const int lr = lane & 15, lg = lane >> 4;
  const int tb = w * 16;
  const int grow = b * 1280 + l0 + tb;

  f32x4 accl[4], accg[4];
#pragma unroll
  for (int nt = 0; nt < 4; ++nt) { f32x4 z = {0,0,0,0}; accl[nt] = z; accg[nt] = z; }
#pragma unroll
  for (int ks = 0; ks < 2; ++ks) {
    bf16x8 al = *(const bf16x8*)(AOl + (grow + lr) * 64 + ks * 32 + lg * 8);
    bf16x8 ag = *(const bf16x8*)(AOg + (grow + lr) * 64 + ks * 32 + lg * 8);
#pragma unroll
    for (int nt = 0; nt < 4; ++nt) {
      bf16x8 bl = *(const bf16x8*)(Wlout + (nt * 16 + lr) * 64 + ks * 32 + lg * 8);
      bf16x8 bg = *(const bf16x8*)(Wgout + (nt * 16 + lr) * 64 + ks * 32 + lg * 8);
      accl[nt] = MF(al, bl, accl[nt]);
      accg[nt] = MF(ag, bg, accg[nt]);
    }
  }
#pragma unroll
  for (int nt = 0; nt < 4; ++nt) {
    const int col = nt * 16 + lr;
    const float bl = lb_out[col], bg = gb_out[col];
    f32x4 xr = *(const f32x4*)&xso[col][tb + lg * 4];
#pragma unroll
    for (int r = 0; r < 4; ++r) {
      accl[nt][r] += bl + xr[r];
      accg[nt][r] += bg + xr[r];
    }
  }
  auto LN = [&](f32x4* a, const float* gam, const float* bet) {
    float gv[4], bv[4];
#pragma unroll
    for (int nt = 0; nt < 4; ++nt) { gv[nt] = gam[nt * 16 + lr]; bv[nt] = bet[nt * 16 + lr]; }
#pragma unroll
    for (int r = 0; r < 4; ++r) {
      float s = a[0][r] + a[1][r] + a[2][r] + a[3][r];
      s += __shfl_xor(s, 1); s += __shfl_xor(s, 2);
      s += __shfl_xor(s, 4); s += __shfl_xor(s, 8);
      const float mu = s * 0.015625f;
      float q = 0.f;
#pragma unroll
      for (int nt = 0; nt < 4; ++nt) { const float cv = a[nt][r] - mu; q = fmaf(cv, cv, q); }
      q += __shfl_xor(q, 1); q += __shfl_xor(q, 2);
      q += __shfl_xor(q, 4); q += __shfl_xor(q, 8);
      const float rsq = rsqrtf(q * 0.015625f + 1e-5f);
#pragma unroll
      for (int nt = 0; nt < 4; ++nt)
        a[nt][r] = (a[nt][r] - mu) * rsq * gv[nt] + bv[nt];
    }
  };
  LN(accl, g1, b1);
  LN(accg, g2, b2);
  f32x4 fus[4];
#pragma unroll
  for (int nt = 0; nt < 4; ++nt) {
    const int col = nt * 16 + lr;
    const float al_ = 1.f / (1.f + __expf(-lwt[col]));
#pragma unroll
    for (int r = 0; r < 4; ++r)
      fus[nt][r] = al_ * accl[nt][r] + (1.f - al_) * accg[nt][r];
  }
#pragma unroll
  for (int nt = 0; nt < 4; ++nt)
#pragma unroll
    for (int r = 0; r < 4; ++r) {
      const int ltok = tb + lg * 4 + r;
      const int byteoff = ((ltok * 64 + nt * 16 + lr) * 2) ^ ((ltok & 7) << 4);
      *(u16*)((char*)Ft + byteoff) = f2bf(fus[nt][r]);
    }
  asm volatile("" ::: "memory");
  __syncthreads();
  f32x4 hcc[8];
#pragma unroll
  for (int nt = 0; nt < 8; ++nt) { f32x4 z = {0,0,0,0}; hcc[nt] = z; }
#pragma unroll
  for (int ks = 0; ks < 2; ++ks) {
    const int ltokA = tb + lr;
    const int abyte = (ltokA * 128 + ks * 64 + lg * 16) ^ ((ltokA & 7) << 4);
    bf16x8 af = *(const bf16x8*)((char*)Ft + abyte);
#pragma unroll
    for (int nt = 0; nt < 8; ++nt) {
      bf16x8 bw = *(const bf16x8*)(W1b + (nt * 16 + lr) * 64 + ks * 32 + lg * 8);
      hcc[nt] = MF(af, bw, hcc[nt]);
    }
  }
#pragma unroll
  for (int nt = 0; nt < 8; ++nt) {
    const int f = nt * 16 + lr;
    const float bbv = bf1[f];
#pragma unroll
    for (int r = 0; r < 4; ++r) {
      const float v = fmaxf(hcc[nt][r] + bbv, 0.f);
      const int ltok = tb + lg * 4 + r;
      const int byteoff = ((ltok * 256 + f * 2)) ^ ((ltok & 7) << 4);
      *(u16*)((char*)Ht + byteoff) = f2bf(v);
    }
  }
  asm volatile("" ::: "memory");
  f32x4 occ[4];
#pragma unroll
  for (int nt = 0; nt < 4; ++nt) { f32x4 z = {0,0,0,0}; occ[nt] = z; }
#pragma unroll
  for (int ks = 0; ks < 4; ++ks) {
    const int ltokA = tb + lr;
    const int abyte = (ltokA * 256 + ks * 64 + lg * 16) ^ ((ltokA & 7) << 4);
    bf16x8 af = *(const bf16x8*)((char*)Ht + abyte);
#pragma unroll
    for (int nt = 0; nt < 4; ++nt) {
      bf16x8 bw = *(const bf16x8*)(W2b + (nt * 16 + lr) * 128 + ks * 32 + lg * 8);
      occ[nt] = MF(af, bw, occ[nt]);
    }
  }
#pragma unroll
  for (int nt = 0; nt < 4; ++nt) {
    const float bb2 = bf2[nt * 16 + lr];
#pragma unroll
    for (int r = 0; r < 4; ++r) occ[nt][r] += bb2 + fus[nt][r];
  }
  LN(occ, g3, b3);
#pragma unroll
  for (int nt = 0; nt < 4; ++nt)
#pragma unroll
    for (int r = 0; r < 4; ++r)
      xso[nt * 16 + lr][tb + lg * 4 + r] = occ[nt][r];
  __syncthreads();
  for (int i = t; i < 4096; i += 256) {
    const int d = i >> 6, tok = i & 63;
    out[(b * 64 + d) * 1280 + l0 + tok] = xso[d][tok];
  }
}

extern "C" void kernel_launch(void* const* d_in, const int* in_sizes, int n_in,
                              void* d_out, int out_size, void* d_ws,
                              size_t ws_size, hipStream_t stream) {
  const float* x      = (const float*)d_in[0];
  const float* lw_in  = (const float*)d_in[1];
  const float* lb_in  = (const float*)d_in[2];
  const float* lw_out = (const float*)d_in[3];
  const float* lb_out = (const float*)d_in[4];
  const float* gw_in  = (const float*)d_in[5];
  const float* gb_in  = (const float*)d_in[6];
  const float* gw_out = (const float*)d_in[7];
  const float* gb_out = (const float*)d_in[8];
  const float* lwt    = (const float*)d_in[9];
  const float* g1 = (const float*)d_in[10]; const float* b1 = (const float*)d_in[11];
  const float* g2 = (const float*)d_in[12]; const float* b2 = (const float*)d_in[13];
  const float* g3 = (const float*)d_in[14]; const float* b3 = (const float*)d_in[15];
  const float* w1 = (const float*)d_in[16]; const float* bf1 = (const float*)d_in[17];
  const float* w2 = (const float*)d_in[18]; const float* bf2 = (const float*)d_in[19];
  float* out = (float*)d_out;

  u16* XT    = (u16*)d_ws;            // 1,310,720
  u16* QKV   = XT + 1310720;          // 7,864,320
  u16* AOl   = QKV + 7864320;         // 1,310,720
  u16* AOg   = AOl + 1310720;         // 1,310,720
  u16* Wqkv  = AOg + 1310720;         // 24,576
  u16* Wlout = Wqkv + 24576;          // 4,096
  u16* Wgout = Wlout + 4096;          // 4,096
  u16* W1b   = Wgout + 4096;          // 8,192
  u16* W2b   = W1b + 8192;            // 8,192

  dim3 blk(256);
  prep_kernel<<<dim3(344), blk, 0, stream>>>(x, lw_in, gw_in, lw_out, gw_out,
                                             w1, w2, XT, Wqkv, Wlout, Wgout, W1b, W2b);
  qkv_gemm<<<dim3(320, 4), blk, 0, stream>>>(XT, Wqkv, lb_in, gb_in, QKV);
  latt<<<dim3(640), blk, 0, stream>>>(QKV, AOl);
  gatt<<<dim3(10, 128), dim3(512), 0, stream>>>(QKV, AOg);
  tail_kernel<<<dim3(20, 16), blk, 0, stream>>>(
      AOl, AOg, Wlout, Wgout, W1b, W2b, lb_out, gb_out, lwt,
      g1, b1, g2, b2, g3, b3, bf1, bf2, x, out);
}

// Round 6
// 79.573 us; speedup vs baseline: 1.5757x; 1.5757x over previous
//
#include <hip/hip_runtime.h>
#include <math.h>

typedef short bf16x8 __attribute__((ext_vector_type(8)));
typedef float f32x4 __attribute__((ext_vector_type(4)));
typedef unsigned short u16;
typedef unsigned int u32;

#define RFL(x) __builtin_amdgcn_readfirstlane(x)

static __device__ __forceinline__ float bf2f(u16 s) {
  union { u32 u; float f; } c; c.u = ((u32)s) << 16; return c.f;
}
static __device__ __forceinline__ u16 f2bf(float f) {
  union { float f; u32 u; } c; c.f = f;
  u32 u = c.u + 0x7fffu + ((c.u >> 16) & 1u);
  return (u16)(u >> 16);
}
static __device__ __forceinline__ u32 pk2(float lo, float hi) {
  u32 r;
  asm("v_cvt_pk_bf16_f32 %0, %1, %2" : "=v"(r) : "v"(lo), "v"(hi));
  return r;
}
static __device__ __forceinline__ f32x4 MF(bf16x8 a, bf16x8 b, f32x4 c) {
  return __builtin_amdgcn_mfma_f32_16x16x32_bf16(a, b, c, 0, 0, 0);
}

// B=16, D=64, L=1280, H=8, hd=8, WIN=5, DFF=128
// Token-major layouts: XT[20480][64] bf16; QKV[20480][384] bf16
//   cols: [0:64)Qloc(*sc) [64:128)Kloc [128:192)Vloc [192:256)Qg(*sc*log2e)
//         [256:320)Kg [320:384)Vg
// MFMA 16x16x32 bf16: A: lane->m=l&15,k=8*(l>>4)+j ; B: lane->k=8*(l>>4)+j,n=l&15
//   C/D: lane,reg r -> row=4*(l>>4)+r, col=l&15

// ============ K0: x -> XT bf16 (transpose) + weights -> bf16 ============
__global__ __launch_bounds__(256) void prep_kernel(
    const float* __restrict__ x,
    const float* __restrict__ lw_in, const float* __restrict__ gw_in,
    const float* __restrict__ lw_out, const float* __restrict__ gw_out,
    const float* __restrict__ w1, const float* __restrict__ w2,
    u16* __restrict__ XT, u16* __restrict__ Wqkv,
    u16* __restrict__ Wlout, u16* __restrict__ Wgout,
    u16* __restrict__ W1b, u16* __restrict__ W2b) {
  const int t = threadIdx.x;
  if (blockIdx.x < 320) {
    __shared__ __align__(16) float xs[64][68];
    const int b = blockIdx.x / 20, l0 = (blockIdx.x % 20) * 64;
    for (int i = t; i < 4096; i += 256) {
      const int d = i >> 6, tok = i & 63;
      xs[tok][d] = x[(b * 64 + d) * 1280 + l0 + tok];
    }
    __syncthreads();
    for (int i = t; i < 512; i += 256) {
      const int tok = i >> 3, c8 = (i & 7) * 8;
      union { bf16x8 v; u32 u[4]; } o;
      const float* src = &xs[tok][c8];
      o.u[0] = pk2(src[0], src[1]); o.u[1] = pk2(src[2], src[3]);
      o.u[2] = pk2(src[4], src[5]); o.u[3] = pk2(src[6], src[7]);
      *(bf16x8*)(XT + (b * 1280 + l0 + tok) * 64 + c8) = o.v;
    }
  } else {
    const int wb = blockIdx.x - 320;
    for (int f = wb * 256 + t; f < 49152; f += 24 * 256) {
      if (f < 12288)      Wqkv[f] = f2bf(lw_in[f]);
      else if (f < 24576) Wqkv[f] = f2bf(gw_in[f - 12288]);
      else if (f < 28672) Wlout[f - 24576] = f2bf(lw_out[f - 24576]);
      else if (f < 32768) Wgout[f - 28672] = f2bf(gw_out[f - 28672]);
      else if (f < 40960) W1b[f - 32768] = f2bf(w1[f - 32768]);
      else                W2b[f - 40960] = f2bf(w2[f - 40960]);
    }
  }
}

// ============ K1: QKV GEMM (local+global fused), M=20480 N=384 K=64 ======
__global__ __launch_bounds__(256) void qkv_gemm(
    const u16* __restrict__ XT, const u16* __restrict__ Wqkv,
    const float* __restrict__ lb_in, const float* __restrict__ gb_in,
    u16* __restrict__ QKV) {
  const int t = threadIdx.x;
  const int lane = t & 63, w = RFL(t >> 6);
  const int lr = lane & 15, lg = lane >> 4;
  const int m0 = blockIdx.x * 64 + (w & 1) * 32;
  const int n0 = blockIdx.y * 96 + (w >> 1) * 48;
  bf16x8 a[2][2], bb[3][2];
#pragma unroll
  for (int mt = 0; mt < 2; ++mt)
#pragma unroll
    for (int ks = 0; ks < 2; ++ks)
      a[mt][ks] = *(const bf16x8*)(XT + (m0 + mt * 16 + lr) * 64 + ks * 32 + lg * 8);
#pragma unroll
  for (int nt = 0; nt < 3; ++nt)
#pragma unroll
    for (int ks = 0; ks < 2; ++ks)
      bb[nt][ks] = *(const bf16x8*)(Wqkv + (n0 + nt * 16 + lr) * 64 + ks * 32 + lg * 8);
  f32x4 acc[2][3];
#pragma unroll
  for (int mt = 0; mt < 2; ++mt)
#pragma unroll
    for (int nt = 0; nt < 3; ++nt) {
      f32x4 z = {0.f, 0.f, 0.f, 0.f};
      acc[mt][nt] = z;
#pragma unroll
      for (int ks = 0; ks < 2; ++ks)
        acc[mt][nt] = MF(a[mt][ks], bb[nt][ks], acc[mt][nt]);
    }
#pragma unroll
  for (int nt = 0; nt < 3; ++nt) {
    const int col = n0 + nt * 16 + lr;
    const float bias = (col < 192) ? lb_in[col] : gb_in[col - 192];
    // fold softmax scale into Q (local: sc; global: sc*log2e for exp2)
    const float scale = (col < 64) ? 0.35355339059327373f
                      : ((col >= 192 && col < 256) ? 0.51010407600615432f : 1.f);
#pragma unroll
    for (int mt = 0; mt < 2; ++mt)
#pragma unroll
      for (int r = 0; r < 4; ++r) {
        const int row = m0 + mt * 16 + 4 * lg + r;
        QKV[row * 384 + col] = f2bf((acc[mt][nt][r] + bias) * scale);
      }
  }
}

// ============ K2: local windowed attention (WIN=5, Q pre-scaled) =========
__global__ __launch_bounds__(256) void latt(const u16* __restrict__ QKV,
                                            u16* __restrict__ AOl) {
  const int g = blockIdx.x * 256 + threadIdx.x;
  const int qi = g % 5, h = (g / 5) & 7, wi = (g / 40) & 255, b = g / 10240;
  const int row = b * 1280 + wi * 5 + qi;
  float q[8];
  {
    bf16x8 qv = *(const bf16x8*)(QKV + row * 384 + h * 8);
#pragma unroll
    for (int d = 0; d < 8; ++d) q[d] = bf2f((u16)qv[d]);
  }
  float p[5], sum = 0.f;
#pragma unroll
  for (int j = 0; j < 5; ++j) {
    const int krow = b * 1280 + wi * 5 + j;
    bf16x8 kv = *(const bf16x8*)(QKV + krow * 384 + 64 + h * 8);
    float s = 0.f;
#pragma unroll
    for (int d = 0; d < 8; ++d) s = fmaf(q[d], bf2f((u16)kv[d]), s);
    p[j] = __expf(s); sum += p[j];
  }
  const float inv = 1.f / sum;
  float o[8] = {0, 0, 0, 0, 0, 0, 0, 0};
#pragma unroll
  for (int j = 0; j < 5; ++j) {
    const int vrow = b * 1280 + wi * 5 + j;
    bf16x8 vv = *(const bf16x8*)(QKV + vrow * 384 + 128 + h * 8);
#pragma unroll
    for (int d = 0; d < 8; ++d) o[d] = fmaf(p[j], bf2f((u16)vv[d]), o[d]);
  }
  union { bf16x8 v; u32 u[4]; } ov;
  ov.u[0] = pk2(o[0] * inv, o[1] * inv); ov.u[1] = pk2(o[2] * inv, o[3] * inv);
  ov.u[2] = pk2(o[4] * inv, o[5] * inv); ov.u[3] = pk2(o[6] * inv, o[7] * inv);
  *(bf16x8*)(AOl + row * 64 + h * 8) = ov.v;
}

// ============ K3: global attention, MFMA flash, zero-P-traffic ============
// K stored PERMUTED in LDS: position pos = (l&~31) + tile*16 + m where
//   tile=(k5>>2)&1, m=(k5&3)+4*(k5>>3), k5=l&31. Then S-tile0 row m holds
//   key 8*(m>>2)+(m&3), S-tile1 row m holds key 8*(m>>2)+(m&3)+4, so lane
//   (lg,c)'s exp2'd outputs (s0[0..3], s1[0..3]) are exactly keys
//   8lg+0..7 for q-col c = the PV B-fragment slots. pk2 packs them
//   in-register: NO LDS round trip, no cross-lane move.
// Q-side (not K-side) is zeroed for lg>=1, so kf reads need no zero pad and
// all 64 lanes read positions jt*32+c (lanes 16+ broadcast, finite garbage
// times Q=0 contributes 0).
// VT rows d=0..7 = V^T, row 8 = ones (PV row 8 = softmax denominator).
// VT stride 1320 u16 = 2640 B: 16B-aligned, quad stride 5 mod 8 ->
// conflict-free b128 reads (4 lanes/quad exactly).
__global__ __launch_bounds__(512) void gatt(const u16* __restrict__ QKV,
                                            u16* __restrict__ AOg) {
  __shared__ __align__(16) u16 Klds[1280 * 8];  // permuted K rows
  __shared__ __align__(16) u16 VT[9 * 1320];    // V^T d=0..7; row 8 = ones
  const int t = threadIdx.x;
  const int b = blockIdx.y >> 3, h = blockIdx.y & 7;
  for (int l = t; l < 1280; l += 512) {
    const int src = (b * 1280 + l) * 384 + h * 8;
    bf16x8 kv = *(const bf16x8*)(QKV + src + 256);
    bf16x8 vv = *(const bf16x8*)(QKV + src + 320);
    const int k5 = l & 31;
    const int pos = (l & ~31) + (((k5 >> 2) & 1) << 4) + (k5 & 3) + ((k5 >> 3) << 2);
    *(bf16x8*)(Klds + pos * 8) = kv;
#pragma unroll
    for (int d = 0; d < 8; ++d) VT[d * 1320 + l] = (u16)vv[d];
  }
  for (int l = t; l < 1320; l += 512) VT[8 * 1320 + l] = 0x3F80;  // ones row
  __syncthreads();
  const int lane = t & 63, w = RFL(t >> 6);
  const int c = lane & 15, lg = lane >> 4;
  const int q0 = blockIdx.x * 128 + w * 16;
  const int qrow = b * 1280 + q0 + c;
  const bf16x8 qv = *(const bf16x8*)(QKV + qrow * 384 + 192 + h * 8);
  const bf16x8 qz = {0, 0, 0, 0, 0, 0, 0, 0};
  const bf16x8 qf = (lg == 0) ? qv : qz;       // zero Q for k-dims 8..31
  const u16* kp = Klds + c * 8;                // all lanes: position jt*32+c
  const int vrow = (c < 8) ? c : 8;
  const u16* vp = VT + vrow * 1320 + lg * 8;
  f32x4 oacc = {0.f, 0.f, 0.f, 0.f};
#pragma unroll 4
  for (int jt = 0; jt < 40; ++jt) {
    bf16x8 kf0 = *(const bf16x8*)kp;           // tile0 rows (bcast over lg)
    bf16x8 kf1 = *(const bf16x8*)(kp + 128);   // tile1 rows
    f32x4 z = {0.f, 0.f, 0.f, 0.f};
    f32x4 s0 = MF(kf0, qf, z);   // S rows: keys 8lg + (0..3) at reg r
    f32x4 s1 = MF(kf1, qf, z);   // S rows: keys 8lg + (4..7)
    const float p0 = __builtin_amdgcn_exp2f(s0[0]);
    const float p1 = __builtin_amdgcn_exp2f(s0[1]);
    const float p2 = __builtin_amdgcn_exp2f(s0[2]);
    const float p3 = __builtin_amdgcn_exp2f(s0[3]);
    const float p4 = __builtin_amdgcn_exp2f(s1[0]);
    const float p5 = __builtin_amdgcn_exp2f(s1[1]);
    const float p6 = __builtin_amdgcn_exp2f(s1[2]);
    const float p7 = __builtin_amdgcn_exp2f(s1[3]);
    union { u32 u[4]; bf16x8 v; } pb;          // B-frag: k=8lg+j, n=c
    pb.u[0] = pk2(p0, p1);
    pb.u[1] = pk2(p2, p3);
    pb.u[2] = pk2(p4, p5);
    pb.u[3] = pk2(p6, p7);
    bf16x8 vf = *(const bf16x8*)vp;            // A: V^T[d][keys 32jt+8lg+..]
    oacc = MF(vf, pb.v, oacc);                 // out^T[d][q]; row 8 = sum P
    kp += 256; vp += 32;
  }
  const float ssum = __shfl(oacc[0], 32 + c);  // D[8][c] lives in lane 32+c
  const float inv = 1.f / ssum;
  if (lg < 2) {                                // d = 4*lg + r in [0,8)
    const int base = qrow * 64 + h * 8 + lg * 4;
    *(u32*)(AOg + base) = pk2(oacc[0] * inv, oacc[1] * inv);
    *(u32*)(AOg + base + 2) = pk2(oacc[2] * inv, oacc[3] * inv);
  }
}

// ============ K4: proj+res+LN (x2) + gate + FFN + LN3 + transpose ========
__global__ __launch_bounds__(256) void tail_kernel(
    const u16* __restrict__ AOl, const u16* __restrict__ AOg,
    const u16* __restrict__ Wlout, const u16* __restrict__ Wgout,
    const u16* __restrict__ W1b, const u16* __restrict__ W2b,
    const float* __restrict__ lb_out, const float* __restrict__ gb_out,
    const float* __restrict__ lwt,
    const float* __restrict__ g1, const float* __restrict__ b1,
    const float* __restrict__ g2, const float* __restrict__ b2,
    const float* __restrict__ g3, const float* __restrict__ b3,
    const float* __restrict__ bf1, const float* __restrict__ bf2,
    const float* __restrict__ x, float* __restrict__ out) {
  __shared__ __align__(16) float xso[64][68];   // residual in, out^T at end
  __shared__ __align__(16) u16 Ft[64 * 64];     // fused (XOR-swizzled)
  __shared__ __align__(16) u16 Ht[64 * 128];    // ffn hidden (XOR-swizzled)
  const int t = threadIdx.x;
  const int b = blockIdx.y, l0 = blockIdx.x * 64;
  for (int i = t; i < 4096; i += 256) {
    const int d = i >> 6, tok = i & 63;
    xso[d][tok] = x[(b * 64 + d) * 1280 + l0 + tok];
  }
  __syncthreads();
  const int lane = t & 63, w = RFL(t >> 6);
  const int lr = lane & 15, lg = lane >> 4;
  const int tb = w * 16;
  const int grow = b * 1280 + l0 + tb;

  f32x4 accl[4], accg[4];
#pragma unroll
  for (int nt = 0; nt < 4; ++nt) { f32x4 z = {0,0,0,0}; accl[nt] = z; accg[nt] = z; }
#pragma unroll
  for (int ks = 0; ks < 2; ++ks) {
    bf16x8 al = *(const bf16x8*)(AOl + (grow + lr) * 64 + ks * 32 + lg * 8);
    bf16x8 ag = *(const bf16x8*)(AOg + (grow + lr) * 64 + ks * 32 + lg * 8);
#pragma unroll
    for (int nt = 0; nt < 4; ++nt) {
      bf16x8 bl = *(const bf16x8*)(Wlout + (nt * 16 + lr) * 64 + ks * 32 + lg * 8);
      bf16x8 bg = *(const bf16x8*)(Wgout + (nt * 16 + lr) * 64 + ks * 32 + lg * 8);
      accl[nt] = MF(al, bl, accl[nt]);
      accg[nt] = MF(ag, bg, accg[nt]);
    }
  }
#pragma unroll
  for (int nt = 0; nt < 4; ++nt) {
    const int col = nt * 16 + lr;
    const float bl = lb_out[col], bg = gb_out[col];
    f32x4 xr = *(const f32x4*)&xso[col][tb + lg * 4];
#pragma unroll
    for (int r = 0; r < 4; ++r) {
      accl[nt][r] += bl + xr[r];
      accg[nt][r] += bg + xr[r];
    }
  }
  auto LN = [&](f32x4* a, const float* gam, const float* bet) {
    float gv[4], bv[4];
#pragma unroll
    for (int nt = 0; nt < 4; ++nt) { gv[nt] = gam[nt * 16 + lr]; bv[nt] = bet[nt * 16 + lr]; }
#pragma unroll
    for (int r = 0; r < 4; ++r) {
      float s = a[0][r] + a[1][r] + a[2][r] + a[3][r];
      s += __shfl_xor(s, 1); s += __shfl_xor(s, 2);
      s += __shfl_xor(s, 4); s += __shfl_xor(s, 8);
      const float mu = s * 0.015625f;
      float q = 0.f;
#pragma unroll
      for (int nt = 0; nt < 4; ++nt) { const float cv = a[nt][r] - mu; q = fmaf(cv, cv, q); }
      q += __shfl_xor(q, 1); q += __shfl_xor(q, 2);
      q += __shfl_xor(q, 4); q += __shfl_xor(q, 8);
      const float rsq = rsqrtf(q * 0.015625f + 1e-5f);
#pragma unroll
      for (int nt = 0; nt < 4; ++nt)
        a[nt][r] = (a[nt][r] - mu) * rsq * gv[nt] + bv[nt];
    }
  };
  LN(accl, g1, b1);
  LN(accg, g2, b2);
  f32x4 fus[4];
#pragma unroll
  for (int nt = 0; nt < 4; ++nt) {
    const int col = nt * 16 + lr;
    const float al_ = 1.f / (1.f + __expf(-lwt[col]));
#pragma unroll
    for (int r = 0; r < 4; ++r)
      fus[nt][r] = al_ * accl[nt][r] + (1.f - al_) * accg[nt][r];
  }
#pragma unroll
  for (int nt = 0; nt < 4; ++nt)
#pragma unroll
    for (int r = 0; r < 4; ++r) {
      const int ltok = tb + lg * 4 + r;
      const int byteoff = ((ltok * 64 + nt * 16 + lr) * 2) ^ ((ltok & 7) << 4);
      *(u16*)((char*)Ft + byteoff) = f2bf(fus[nt][r]);
    }
  asm volatile("" ::: "memory");
  __syncthreads();
  f32x4 hcc[8];
#pragma unroll
  for (int nt = 0; nt < 8; ++nt) { f32x4 z = {0,0,0,0}; hcc[nt] = z; }
#pragma unroll
  for (int ks = 0; ks < 2; ++ks) {
    const int ltokA = tb + lr;
    const int abyte = (ltokA * 128 + ks * 64 + lg * 16) ^ ((ltokA & 7) << 4);
    bf16x8 af = *(const bf16x8*)((char*)Ft + abyte);
#pragma unroll
    for (int nt = 0; nt < 8; ++nt) {
      bf16x8 bw = *(const bf16x8*)(W1b + (nt * 16 + lr) * 64 + ks * 32 + lg * 8);
      hcc[nt] = MF(af, bw, hcc[nt]);
    }
  }
#pragma unroll
  for (int nt = 0; nt < 8; ++nt) {
    const int f = nt * 16 + lr;
    const float bbv = bf1[f];
#pragma unroll
    for (int r = 0; r < 4; ++r) {
      const float v = fmaxf(hcc[nt][r] + bbv, 0.f);
      const int ltok = tb + lg * 4 + r;
      const int byteoff = ((ltok * 256 + f * 2)) ^ ((ltok & 7) << 4);
      *(u16*)((char*)Ht + byteoff) = f2bf(v);
    }
  }
  asm volatile("" ::: "memory");
  f32x4 occ[4];
#pragma unroll
  for (int nt = 0; nt < 4; ++nt) { f32x4 z = {0,0,0,0}; occ[nt] = z; }
#pragma unroll
  for (int ks = 0; ks < 4; ++ks) {
    const int ltokA = tb + lr;
    const int abyte = (ltokA * 256 + ks * 64 + lg * 16) ^ ((ltokA & 7) << 4);
    bf16x8 af = *(const bf16x8*)((char*)Ht + abyte);
#pragma unroll
    for (int nt = 0; nt < 4; ++nt) {
      bf16x8 bw = *(const bf16x8*)(W2b + (nt * 16 + lr) * 128 + ks * 32 + lg * 8);
      occ[nt] = MF(af, bw, occ[nt]);
    }
  }
#pragma unroll
  for (int nt = 0; nt < 4; ++nt) {
    const float bb2 = bf2[nt * 16 + lr];
#pragma unroll
    for (int r = 0; r < 4; ++r) occ[nt][r] += bb2 + fus[nt][r];
  }
  LN(occ, g3, b3);
#pragma unroll
  for (int nt = 0; nt < 4; ++nt)
#pragma unroll
    for (int r = 0; r < 4; ++r)
      xso[nt * 16 + lr][tb + lg * 4 + r] = occ[nt][r];
  __syncthreads();
  for (int i = t; i < 4096; i += 256) {
    const int d = i >> 6, tok = i & 63;
    out[(b * 64 + d) * 1280 + l0 + tok] = xso[d][tok];
  }
}

extern "C" void kernel_launch(void* const* d_in, const int* in_sizes, int n_in,
                              void* d_out, int out_size, void* d_ws,
                              size_t ws_size, hipStream_t stream) {
  const float* x      = (const float*)d_in[0];
  const float* lw_in  = (const float*)d_in[1];
  const float* lb_in  = (const float*)d_in[2];
  const float* lw_out = (const float*)d_in[3];
  const float* lb_out = (const float*)d_in[4];
  const float* gw_in  = (const float*)d_in[5];
  const float* gb_in  = (const float*)d_in[6];
  const float* gw_out = (const float*)d_in[7];
  const float* gb_out = (const float*)d_in[8];
  const float* lwt    = (const float*)d_in[9];
  const float* g1 = (const float*)d_in[10]; const float* b1 = (const float*)d_in[11];
  const float* g2 = (const float*)d_in[12]; const float* b2 = (const float*)d_in[13];
  const float* g3 = (const float*)d_in[14]; const float* b3 = (const float*)d_in[15];
  const float* w1 = (const float*)d_in[16]; const float* bf1 = (const float*)d_in[17];
  const float* w2 = (const float*)d_in[18]; const float* bf2 = (const float*)d_in[19];
  float* out = (float*)d_out;

  u16* XT    = (u16*)d_ws;            // 1,310,720
  u16* QKV   = XT + 1310720;          // 7,864,320
  u16* AOl   = QKV + 7864320;         // 1,310,720
  u16* AOg   = AOl + 1310720;         // 1,310,720
  u16* Wqkv  = AOg + 1310720;         // 24,576
  u16* Wlout = Wqkv + 24576;          // 4,096
  u16* Wgout = Wlout + 4096;          // 4,096
  u16* W1b   = Wgout + 4096;          // 8,192
  u16* W2b   = W1b + 8192;            // 8,192

  dim3 blk(256);
  prep_kernel<<<dim3(344), blk, 0, stream>>>(x, lw_in, gw_in, lw_out, gw_out,
                                             w1, w2, XT, Wqkv, Wlout, Wgout, W1b, W2b);
  qkv_gemm<<<dim3(320, 4), blk, 0, stream>>>(XT, Wqkv, lb_in, gb_in, QKV);
  latt<<<dim3(640), blk, 0, stream>>>(QKV, AOl);
  gatt<<<dim3(10, 128), dim3(512), 0, stream>>>(QKV, AOg);
  tail_kernel<<<dim3(20, 16), blk, 0, stream>>>(
      AOl, AOg, Wlout, Wgout, W1b, W2b, lb_out, gb_out, lwt,
      g1, b1, g2, b2, g3, b3, bf1, bf2, x, out);
}

// Round 7
// 73.860 us; speedup vs baseline: 1.6976x; 1.0774x over previous
//
#include <hip/hip_runtime.h>
#include <math.h>

typedef short bf16x8 __attribute__((ext_vector_type(8)));
typedef float f32x4 __attribute__((ext_vector_type(4)));
typedef unsigned short u16;
typedef unsigned int u32;

#define RFL(x) __builtin_amdgcn_readfirstlane(x)

static __device__ __forceinline__ float bf2f(u16 s) {
  union { u32 u; float f; } c; c.u = ((u32)s) << 16; return c.f;
}
static __device__ __forceinline__ u16 f2bf(float f) {
  union { float f; u32 u; } c; c.f = f;
  u32 u = c.u + 0x7fffu + ((c.u >> 16) & 1u);
  return (u16)(u >> 16);
}
static __device__ __forceinline__ u32 pk2(float lo, float hi) {
  u32 r;
  asm("v_cvt_pk_bf16_f32 %0, %1, %2" : "=v"(r) : "v"(lo), "v"(hi));
  return r;
}
static __device__ __forceinline__ f32x4 MF(bf16x8 a, bf16x8 b, f32x4 c) {
  return __builtin_amdgcn_mfma_f32_16x16x32_bf16(a, b, c, 0, 0, 0);
}

// B=16, D=64, L=1280, H=8, hd=8, WIN=5, DFF=128
// QKV[20480][384] bf16 cols: [0:64)Qloc(*sc) [64:128)Kloc [128:192)Vloc
//   [192:256)Qg(*sc*log2e) [256:320)Kg [320:384)Vg
// MFMA 16x16x32 bf16: A: lane->m=l&15,k=8*(l>>4)+j ; B: lane->k=8*(l>>4)+j,n=l&15
//   C/D: lane,reg r -> row=4*(l>>4)+r, col=l&15

// ====== K1: fused x-transpose + bf16 convert + QKV GEMM =================
// 640 blocks x 256: block = (b, 32-token tile). x staged fp32 in LDS,
// packed to XOR-swizzled bf16 tile; weights converted fp32->bf16 in-register
// per wave (L2-resident, no separate prep pass / no XT buffer).
__global__ __launch_bounds__(256) void qkvx(
    const float* __restrict__ x, const float* __restrict__ lw_in,
    const float* __restrict__ gw_in, const float* __restrict__ lb_in,
    const float* __restrict__ gb_in, u16* __restrict__ QKV) {
  __shared__ __align__(16) float xs[32][68];
  __shared__ __align__(16) u16 XTs[32 * 64];   // XOR-swizzled [tok][d]
  const int t = threadIdx.x;
  const int b = blockIdx.x / 40, l0 = (blockIdx.x % 40) * 32;
  for (int i = t; i < 2048; i += 256) {
    const int d = i >> 5, tok = i & 31;
    xs[tok][d] = x[(b * 64 + d) * 1280 + l0 + tok];
  }
  __syncthreads();
  {
    const int tok = t >> 3, c8 = (t & 7) * 8;
    union { bf16x8 v; u32 u[4]; } o;
    const float* src = &xs[tok][c8];
    o.u[0] = pk2(src[0], src[1]); o.u[1] = pk2(src[2], src[3]);
    o.u[2] = pk2(src[4], src[5]); o.u[3] = pk2(src[6], src[7]);
    const int byteoff = (tok * 128 + c8 * 2) ^ ((tok & 7) << 4);
    *(bf16x8*)((char*)XTs + byteoff) = o.v;
  }
  __syncthreads();
  const int lane = t & 63, w = RFL(t >> 6);
  const int lr = lane & 15, lg = lane >> 4;
  const int n0 = w * 96;                        // 4 waves x 96 cols
  bf16x8 a[2][2];
#pragma unroll
  for (int mt = 0; mt < 2; ++mt)
#pragma unroll
    for (int ks = 0; ks < 2; ++ks) {
      const int row = mt * 16 + lr;
      const int abyte = (row * 128 + ks * 64 + lg * 16) ^ ((row & 7) << 4);
      a[mt][ks] = *(const bf16x8*)((char*)XTs + abyte);
    }
  const float* W32 = (n0 < 192) ? lw_in : gw_in;
  const int nb = (n0 < 192) ? n0 : n0 - 192;
  bf16x8 bb[6][2];
#pragma unroll
  for (int nt = 0; nt < 6; ++nt)
#pragma unroll
    for (int ks = 0; ks < 2; ++ks) {
      const float* src = W32 + (nb + nt * 16 + lr) * 64 + ks * 32 + lg * 8;
      const float4 f0 = *(const float4*)src;
      const float4 f1 = *(const float4*)(src + 4);
      union { bf16x8 v; u32 u[4]; } o;
      o.u[0] = pk2(f0.x, f0.y); o.u[1] = pk2(f0.z, f0.w);
      o.u[2] = pk2(f1.x, f1.y); o.u[3] = pk2(f1.z, f1.w);
      bb[nt][ks] = o.v;
    }
  f32x4 acc[2][6];
#pragma unroll
  for (int mt = 0; mt < 2; ++mt)
#pragma unroll
    for (int nt = 0; nt < 6; ++nt) {
      f32x4 z = {0.f, 0.f, 0.f, 0.f};
      acc[mt][nt] = z;
#pragma unroll
      for (int ks = 0; ks < 2; ++ks)
        acc[mt][nt] = MF(a[mt][ks], bb[nt][ks], acc[mt][nt]);
    }
#pragma unroll
  for (int nt = 0; nt < 6; ++nt) {
    const int col = n0 + nt * 16 + lr;
    const float bias = (col < 192) ? lb_in[col] : gb_in[col - 192];
    const float scale = (col < 64) ? 0.35355339059327373f
                      : ((col >= 192 && col < 256) ? 0.51010407600615432f : 1.f);
#pragma unroll
    for (int mt = 0; mt < 2; ++mt)
#pragma unroll
      for (int r = 0; r < 4; ++r) {
        const int row = b * 1280 + l0 + mt * 16 + 4 * lg + r;
        QKV[row * 384 + col] = f2bf((acc[mt][nt][r] + bias) * scale);
      }
  }
}

// ====== K2: fused attention launch =======================================
// grid (13,128) x 512:
//   blockIdx.x < 10 : global attention (R6-proven permuted-K core)
//   else lid<320    : local windowed attention (overlaps gatt)
//   else            : convert tail weights fp32->bf16 (64 blocks)
__global__ __launch_bounds__(512) void attn(
    const u16* __restrict__ QKV, u16* __restrict__ AOl, u16* __restrict__ AOg,
    const float* __restrict__ lw_out, const float* __restrict__ gw_out,
    const float* __restrict__ w1, const float* __restrict__ w2,
    u16* __restrict__ Wlout, u16* __restrict__ Wgout,
    u16* __restrict__ W1b, u16* __restrict__ W2b) {
  __shared__ __align__(16) u16 Klds[1280 * 8];  // permuted K rows
  __shared__ __align__(16) u16 VT[9 * 1320];    // V^T d=0..7; row 8 = ones
  const int t = threadIdx.x;
  if (blockIdx.x < 10) {
    // ---- global attention ----
    const int b = blockIdx.y >> 3, h = blockIdx.y & 7;
    for (int l = t; l < 1280; l += 512) {
      const int src = (b * 1280 + l) * 384 + h * 8;
      bf16x8 kv = *(const bf16x8*)(QKV + src + 256);
      bf16x8 vv = *(const bf16x8*)(QKV + src + 320);
      const int k5 = l & 31;
      const int pos = (l & ~31) + (((k5 >> 2) & 1) << 4) + (k5 & 3) + ((k5 >> 3) << 2);
      *(bf16x8*)(Klds + pos * 8) = kv;
#pragma unroll
      for (int d = 0; d < 8; ++d) VT[d * 1320 + l] = (u16)vv[d];
    }
    for (int l = t; l < 1320; l += 512) VT[8 * 1320 + l] = 0x3F80;  // ones
    __syncthreads();
    const int lane = t & 63, w = RFL(t >> 6);
    const int c = lane & 15, lg = lane >> 4;
    const int q0 = blockIdx.x * 128 + w * 16;
    const int qrow = b * 1280 + q0 + c;
    const bf16x8 qv = *(const bf16x8*)(QKV + qrow * 384 + 192 + h * 8);
    const bf16x8 qz = {0, 0, 0, 0, 0, 0, 0, 0};
    const bf16x8 qf = (lg == 0) ? qv : qz;     // zero Q for k-dims 8..31
    const u16* kp = Klds + c * 8;
    const int vrow = (c < 8) ? c : 8;
    const u16* vp = VT + vrow * 1320 + lg * 8;
    f32x4 oacc = {0.f, 0.f, 0.f, 0.f};
#pragma unroll 4
    for (int jt = 0; jt < 40; ++jt) {
      bf16x8 kf0 = *(const bf16x8*)kp;
      bf16x8 kf1 = *(const bf16x8*)(kp + 128);
      f32x4 z = {0.f, 0.f, 0.f, 0.f};
      f32x4 s0 = MF(kf0, qf, z);   // keys 8lg+(0..3) at reg r, q-col c
      f32x4 s1 = MF(kf1, qf, z);   // keys 8lg+(4..7)
      const float p0 = __builtin_amdgcn_exp2f(s0[0]);
      const float p1 = __builtin_amdgcn_exp2f(s0[1]);
      const float p2 = __builtin_amdgcn_exp2f(s0[2]);
      const float p3 = __builtin_amdgcn_exp2f(s0[3]);
      const float p4 = __builtin_amdgcn_exp2f(s1[0]);
      const float p5 = __builtin_amdgcn_exp2f(s1[1]);
      const float p6 = __builtin_amdgcn_exp2f(s1[2]);
      const float p7 = __builtin_amdgcn_exp2f(s1[3]);
      union { u32 u[4]; bf16x8 v; } pb;        // B-frag: k=8lg+j, n=c
      pb.u[0] = pk2(p0, p1);
      pb.u[1] = pk2(p2, p3);
      pb.u[2] = pk2(p4, p5);
      pb.u[3] = pk2(p6, p7);
      bf16x8 vf = *(const bf16x8*)vp;
      oacc = MF(vf, pb.v, oacc);               // out^T[d][q]; row 8 = sum P
      kp += 256; vp += 32;
    }
    const float ssum = __shfl(oacc[0], 32 + c);
    const float inv = 1.f / ssum;
    if (lg < 2) {
      const int base = qrow * 64 + h * 8 + lg * 4;
      *(u32*)(AOg + base) = pk2(oacc[0] * inv, oacc[1] * inv);
      *(u32*)(AOg + base + 2) = pk2(oacc[2] * inv, oacc[3] * inv);
    }
    return;
  }
  const int lid = (blockIdx.x - 10) * 128 + blockIdx.y;
  if (lid < 320) {
    // ---- local windowed attention (WIN=5, Q pre-scaled) ----
    const int g = lid * 512 + t;
    const int qi = g % 5, h = (g / 5) & 7, wi = (g / 40) & 255, b = g / 10240;
    const int row = b * 1280 + wi * 5 + qi;
    float q[8];
    {
      bf16x8 qv = *(const bf16x8*)(QKV + row * 384 + h * 8);
#pragma unroll
      for (int d = 0; d < 8; ++d) q[d] = bf2f((u16)qv[d]);
    }
    float p[5], sum = 0.f;
#pragma unroll
    for (int j = 0; j < 5; ++j) {
      const int krow = b * 1280 + wi * 5 + j;
      bf16x8 kv = *(const bf16x8*)(QKV + krow * 384 + 64 + h * 8);
      float s = 0.f;
#pragma unroll
      for (int d = 0; d < 8; ++d) s = fmaf(q[d], bf2f((u16)kv[d]), s);
      p[j] = __expf(s); sum += p[j];
    }
    const float inv = 1.f / sum;
    float o[8] = {0, 0, 0, 0, 0, 0, 0, 0};
#pragma unroll
    for (int j = 0; j < 5; ++j) {
      const int vrow = b * 1280 + wi * 5 + j;
      bf16x8 vv = *(const bf16x8*)(QKV + vrow * 384 + 128 + h * 8);
#pragma unroll
      for (int d = 0; d < 8; ++d) o[d] = fmaf(p[j], bf2f((u16)vv[d]), o[d]);
    }
    union { bf16x8 v; u32 u[4]; } ov;
    ov.u[0] = pk2(o[0] * inv, o[1] * inv); ov.u[1] = pk2(o[2] * inv, o[3] * inv);
    ov.u[2] = pk2(o[4] * inv, o[5] * inv); ov.u[3] = pk2(o[6] * inv, o[7] * inv);
    *(bf16x8*)(AOl + row * 64 + h * 8) = ov.v;
  } else {
    // ---- tail weight conversion (finishes long before tail launches) ----
    const int f = (lid - 320) * 512 + t;
    if (f < 4096)       Wlout[f] = f2bf(lw_out[f]);
    else if (f < 8192)  Wgout[f - 4096] = f2bf(gw_out[f - 4096]);
    else if (f < 16384) W1b[f - 8192] = f2bf(w1[f - 8192]);
    else if (f < 24576) W2b[f - 16384] = f2bf(w2[f - 16384]);
  }
}

// ====== K3: proj+res+LN (x2) + gate + FFN + LN3 + transpose ==============
// 1280 blocks x 64 threads (1 wave, 16 tokens) for even CU spread.
__global__ __launch_bounds__(64) void tail_kernel(
    const u16* __restrict__ AOl, const u16* __restrict__ AOg,
    const u16* __restrict__ Wlout, const u16* __restrict__ Wgout,
    const u16* __restrict__ W1b, const u16* __restrict__ W2b,
    const float* __restrict__ lb_out, const float* __restrict__ gb_out,
    const float* __restrict__ lwt,
    const float* __restrict__ g1, const float* __restrict__ b1,
    const float* __restrict__ g2, const float* __restrict__ b2,
    const float* __restrict__ g3, const float* __restrict__ b3,
    const float* __restrict__ bf1, const float* __restrict__ bf2,
    const float* __restrict__ x, float* __restrict__ out) {
  __shared__ __align__(16) float xso[64][20];   // residual in, out^T at end
  __shared__ __align__(16) u16 Ft[16 * 64];     // fused (XOR-swizzled)
  __shared__ __align__(16) u16 Ht[16 * 128];    // ffn hidden (XOR-swizzled)
  const int t = threadIdx.x;
  const int b = blockIdx.y, l0 = blockIdx.x * 16;
  for (int i = t; i < 1024; i += 64) {
    const int d = i >> 4, tok = i & 15;
    xso[d][tok] = x[(b * 64 + d) * 1280 + l0 + tok];
  }
  __syncthreads();
  const int lr = t & 15, lg = (t & 63) >> 4;
  const int grow = b * 1280 + l0;

  f32x4 accl[4], accg[4];
#pragma unroll
  for (int nt = 0; nt < 4; ++nt) { f32x4 z = {0,0,0,0}; accl[nt] = z; accg[nt] = z; }
#pragma unroll
  for (int ks = 0; ks < 2; ++ks) {
    bf16x8 al = *(const bf16x8*)(AOl + (grow + lr) * 64 + ks * 32 + lg * 8);
    bf16x8 ag = *(const bf16x8*)(AOg + (grow + lr) * 64 + ks * 32 + lg * 8);
#pragma unroll
    for (int nt = 0; nt < 4; ++nt) {
      bf16x8 bl = *(const bf16x8*)(Wlout + (nt * 16 + lr) * 64 + ks * 32 + lg * 8);
      bf16x8 bg = *(const bf16x8*)(Wgout + (nt * 16 + lr) * 64 + ks * 32 + lg * 8);
      accl[nt] = MF(al, bl, accl[nt]);
      accg[nt] = MF(ag, bg, accg[nt]);
    }
  }
#pragma unroll
  for (int nt = 0; nt < 4; ++nt) {
    const int col = nt * 16 + lr;
    const float bl = lb_out[col], bg = gb_out[col];
    f32x4 xr = *(const f32x4*)&xso[col][lg * 4];
#pragma unroll
    for (int r = 0; r < 4; ++r) {
      accl[nt][r] += bl + xr[r];
      accg[nt][r] += bg + xr[r];
    }
  }
  auto LN = [&](f32x4* a, const float* gam, const float* bet) {
    float gv[4], bv[4];
#pragma unroll
    for (int nt = 0; nt < 4; ++nt) { gv[nt] = gam[nt * 16 + lr]; bv[nt] = bet[nt * 16 + lr]; }
#pragma unroll
    for (int r = 0; r < 4; ++r) {
      float s = a[0][r] + a[1][r] + a[2][r] + a[3][r];
      s += __shfl_xor(s, 1); s += __shfl_xor(s, 2);
      s += __shfl_xor(s, 4); s += __shfl_xor(s, 8);
      const float mu = s * 0.015625f;
      float q = 0.f;
#pragma unroll
      for (int nt = 0; nt < 4; ++nt) { const float cv = a[nt][r] - mu; q = fmaf(cv, cv, q); }
      q += __shfl_xor(q, 1); q += __shfl_xor(q, 2);
      q += __shfl_xor(q, 4); q += __shfl_xor(q, 8);
      const float rsq = rsqrtf(q * 0.015625f + 1e-5f);
#pragma unroll
      for (int nt = 0; nt < 4; ++nt)
        a[nt][r] = (a[nt][r] - mu) * rsq * gv[nt] + bv[nt];
    }
  };
  LN(accl, g1, b1);
  LN(accg, g2, b2);
  f32x4 fus[4];
#pragma unroll
  for (int nt = 0; nt < 4; ++nt) {
    const int col = nt * 16 + lr;
    const float al_ = 1.f / (1.f + __expf(-lwt[col]));
#pragma unroll
    for (int r = 0; r < 4; ++r)
      fus[nt][r] = al_ * accl[nt][r] + (1.f - al_) * accg[nt][r];
  }
#pragma unroll
  for (int nt = 0; nt < 4; ++nt)
#pragma unroll
    for (int r = 0; r < 4; ++r) {
      const int ltok = lg * 4 + r;
      const int byteoff = (ltok * 128 + (nt * 16 + lr) * 2) ^ ((ltok & 7) << 4);
      *(u16*)((char*)Ft + byteoff) = f2bf(fus[nt][r]);
    }
  asm volatile("" ::: "memory");
  __syncthreads();
  f32x4 hcc[8];
#pragma unroll
  for (int nt = 0; nt < 8; ++nt) { f32x4 z = {0,0,0,0}; hcc[nt] = z; }
#pragma unroll
  for (int ks = 0; ks < 2; ++ks) {
    const int abyte = (lr * 128 + ks * 64 + lg * 16) ^ ((lr & 7) << 4);
    bf16x8 af = *(const bf16x8*)((char*)Ft + abyte);
#pragma unroll
    for (int nt = 0; nt < 8; ++nt) {
      bf16x8 bw = *(const bf16x8*)(W1b + (nt * 16 + lr) * 64 + ks * 32 + lg * 8);
      hcc[nt] = MF(af, bw, hcc[nt]);
    }
  }
#pragma unroll
  for (int nt = 0; nt < 8; ++nt) {
    const int f = nt * 16 + lr;
    const float bbv = bf1[f];
#pragma unroll
    for (int r = 0; r < 4; ++r) {
      const float v = fmaxf(hcc[nt][r] + bbv, 0.f);
      const int ltok = lg * 4 + r;
      const int byteoff = (ltok * 256 + f * 2) ^ ((ltok & 7) << 4);
      *(u16*)((char*)Ht + byteoff) = f2bf(v);
    }
  }
  asm volatile("" ::: "memory");
  f32x4 occ[4];
#pragma unroll
  for (int nt = 0; nt < 4; ++nt) { f32x4 z = {0,0,0,0}; occ[nt] = z; }
#pragma unroll
  for (int ks = 0; ks < 4; ++ks) {
    const int abyte = (lr * 256 + ks * 64 + lg * 16) ^ ((lr & 7) << 4);
    bf16x8 af = *(const bf16x8*)((char*)Ht + abyte);
#pragma unroll
    for (int nt = 0; nt < 4; ++nt) {
      bf16x8 bw = *(const bf16x8*)(W2b + (nt * 16 + lr) * 128 + ks * 32 + lg * 8);
      occ[nt] = MF(af, bw, occ[nt]);
    }
  }
#pragma unroll
  for (int nt = 0; nt < 4; ++nt) {
    const float bb2 = bf2[nt * 16 + lr];
#pragma unroll
    for (int r = 0; r < 4; ++r) occ[nt][r] += bb2 + fus[nt][r];
  }
  LN(occ, g3, b3);
#pragma unroll
  for (int nt = 0; nt < 4; ++nt)
#pragma unroll
    for (int r = 0; r < 4; ++r)
      xso[nt * 16 + lr][lg * 4 + r] = occ[nt][r];
  __syncthreads();
  for (int i = t; i < 1024; i += 64) {
    const int d = i >> 4, tok = i & 15;
    out[(b * 64 + d) * 1280 + l0 + tok] = xso[d][tok];
  }
}

extern "C" void kernel_launch(void* const* d_in, const int* in_sizes, int n_in,
                              void* d_out, int out_size, void* d_ws,
                              size_t ws_size, hipStream_t stream) {
  const float* x      = (const float*)d_in[0];
  const float* lw_in  = (const float*)d_in[1];
  const float* lb_in  = (const float*)d_in[2];
  const float* lw_out = (const float*)d_in[3];
  const float* lb_out = (const float*)d_in[4];
  const float* gw_in  = (const float*)d_in[5];
  const float* gb_in  = (const float*)d_in[6];
  const float* gw_out = (const float*)d_in[7];
  const float* gb_out = (const float*)d_in[8];
  const float* lwt    = (const float*)d_in[9];
  const float* g1 = (const float*)d_in[10]; const float* b1 = (const float*)d_in[11];
  const float* g2 = (const float*)d_in[12]; const float* b2 = (const float*)d_in[13];
  const float* g3 = (const float*)d_in[14]; const float* b3 = (const float*)d_in[15];
  const float* w1 = (const float*)d_in[16]; const float* bf1 = (const float*)d_in[17];
  const float* w2 = (const float*)d_in[18]; const float* bf2 = (const float*)d_in[19];
  float* out = (float*)d_out;

  u16* QKV   = (u16*)d_ws;            // 7,864,320
  u16* AOl   = QKV + 7864320;         // 1,310,720
  u16* AOg   = AOl + 1310720;         // 1,310,720
  u16* Wlout = AOg + 1310720;         // 4,096
  u16* Wgout = Wlout + 4096;          // 4,096
  u16* W1b   = Wgout + 4096;          // 8,192
  u16* W2b   = W1b + 8192;            // 8,192

  qkvx<<<dim3(640), dim3(256), 0, stream>>>(x, lw_in, gw_in, lb_in, gb_in, QKV);
  attn<<<dim3(13, 128), dim3(512), 0, stream>>>(QKV, AOl, AOg, lw_out, gw_out,
                                                w1, w2, Wlout, Wgout, W1b, W2b);
  tail_kernel<<<dim3(80, 16), dim3(64), 0, stream>>>(
      AOl, AOg, Wlout, Wgout, W1b, W2b, lb_out, gb_out, lwt,
      g1, b1, g2, b2, g3, b3, bf1, bf2, x, out);
}